// Round 1
// baseline (754.526 us; speedup 1.0000x reference)
//
#include <hip/hip_runtime.h>

// RRGCN cell update (reference collapses to elementwise LSTM-ish math):
//   S     = X + H
//   g     = sigmoid(S)        (I == F == O, identical math in reference)
//   T     = tanh(S)
//   C_new = g*C + g*T = g*(C + T)
//   H_new = g * tanh(C_new)
// edge_attr / global_attr are dead inputs (identity conv in the source).
// Memory-bound: 3 reads + 2 writes of 204.8 MB fp32 => ~1.02 GB @ ~6.3 TB/s.

__device__ __forceinline__ float sigm_fast(float x) {
    return 1.0f / (1.0f + __expf(-x));
}

// Overflow-safe fast tanh: exp(-2|x|) in (0,1], no inf/NaN for any input.
__device__ __forceinline__ float tanh_fast(float x) {
    float e = __expf(-2.0f * fabsf(x));
    float t = (1.0f - e) / (1.0f + e);
    return copysignf(t, x);
}

__global__ __launch_bounds__(256) void rrgcn_cell_kernel(
    const float4* __restrict__ X,
    const float4* __restrict__ H,
    const float4* __restrict__ C,
    float4* __restrict__ Hn,
    float4* __restrict__ Cn,
    int n4)
{
    int i = blockIdx.x * blockDim.x + threadIdx.x;
    if (i >= n4) return;

    float4 x = X[i];
    float4 h = H[i];
    float4 c = C[i];
    float4 hn, cn;

#define RRGCN_COMP(f)                                  \
    {                                                  \
        float s  = x.f + h.f;                          \
        float g  = sigm_fast(s);                       \
        float t  = tanh_fast(s);                       \
        float cv = g * (c.f + t);                      \
        cn.f = cv;                                     \
        hn.f = g * tanh_fast(cv);                      \
    }
    RRGCN_COMP(x)
    RRGCN_COMP(y)
    RRGCN_COMP(z)
    RRGCN_COMP(w)
#undef RRGCN_COMP

    Hn[i] = hn;
    Cn[i] = cn;
}

extern "C" void kernel_launch(void* const* d_in, const int* in_sizes, int n_in,
                              void* d_out, int out_size, void* d_ws, size_t ws_size,
                              hipStream_t stream) {
    // setup_inputs order: X, edge_attr, global_attr, H, C  (all fp32)
    const float* X = (const float*)d_in[0];
    // d_in[1] = edge_attr (8x64)  -- unused (identity conv)
    // d_in[2] = global_attr (1x8) -- unused
    const float* H = (const float*)d_in[3];
    const float* C = (const float*)d_in[4];

    int n = in_sizes[0];              // 200000 * 256 = 51,200,000 (divisible by 4)
    int n4 = n / 4;

    float* out = (float*)d_out;       // [H_new (n) | C_new (n)]
    float* Hn = out;
    float* Cn = out + n;

    int block = 256;
    int grid = (n4 + block - 1) / block;  // 50000 blocks
    rrgcn_cell_kernel<<<grid, block, 0, stream>>>(
        (const float4*)X, (const float4*)H, (const float4*)C,
        (float4*)Hn, (float4*)Cn, n4);
}